// Round 4
// baseline (257.116 us; speedup 1.0000x reference)
//
#include <hip/hip_runtime.h>
#include <hip/hip_bf16.h>

// Problem constants
#define NN  50000   // nodes
#define FD  128     // features
#define NE  800000  // external edges
#define NEI 400000  // internal edges
#define NG  64      // graphs

// Workspace layout (bytes). [0, ZERO_BYTES) is zeroed each launch.
#define DEG_EXT_OFF 0        // 50000 int
#define DEG_INT_OFF 200704   // 50000 int
#define EZ_OFF      401408   // 64*128 float
#define IZ_OFF      434176   // 64*128 float
#define CNT_OFF     466944   // 64 int
#define ZERO_BYTES  467200
// B fragments: 4 convs x [ (ct 0..7, kc 0..3, part 0..1) x 64 lanes x 8 ushort ]
#define WB_OFF      467200   // 4 * 32768 ushort = 256 KB
#define WCOL_OFF    729344   // 4 * 128 float = 2 KB

typedef short  short8 __attribute__((ext_vector_type(8)));
typedef float  f32x4  __attribute__((ext_vector_type(4)));

union S8 { short8 s; unsigned int u[4]; };

__device__ __forceinline__ unsigned short bf16h(float f) {
  unsigned int u = __float_as_uint(f);
  u += 0x7FFFu + ((u >> 16) & 1u);            // RNE
  return (unsigned short)(u >> 16);
}
__device__ __forceinline__ float bf16tof(unsigned short h) {
  return __uint_as_float(((unsigned int)h) << 16);
}
// packed 2xf32 -> 2xbf16 (v_cvt_pk_bf16_f32), a in low 16, b in high 16
__device__ __forceinline__ unsigned int pk_bf16(float a, float b) {
  __hip_bfloat162 h = __float22bfloat162_rn(make_float2(a, b));
  unsigned int u;
  __builtin_memcpy(&u, &h, 4);
  return u;
}

// -------------------------------------------------------------------------
// Edge histograms: 1.2M fire-and-forget device atomics (softmax([E,1])==1
// -> the message MLP reduces to out-degree counts).  int4 loads.
// -------------------------------------------------------------------------
#define EB_EXT 782   // ceil(200000 int4 / 256)
#define EB_INT 391   // ceil(100000 int4 / 256)

__global__ __launch_bounds__(256) void edge_hist_kernel(
    const int4* __restrict__ ei4, const int4* __restrict__ iei4,
    int* __restrict__ deg_ext, int* __restrict__ deg_int)
{
  const int b = blockIdx.x, t = threadIdx.x;
  if (b < EB_EXT) {
    const int i = b * 256 + t;
    if (i < NE / 4) {
      const int4 v = ei4[i];
      atomicAdd(&deg_ext[v.x], 1);
      atomicAdd(&deg_ext[v.y], 1);
      atomicAdd(&deg_ext[v.z], 1);
      atomicAdd(&deg_ext[v.w], 1);
    }
  } else {
    const int i = (b - EB_EXT) * 256 + t;
    if (i < NEI / 4) {
      const int4 v = iei4[i];
      atomicAdd(&deg_int[v.x], 1);
      atomicAdd(&deg_int[v.y], 1);
      atomicAdd(&deg_int[v.z], 1);
      atomicAdd(&deg_int[v.w], 1);
    }
  }
}

// -------------------------------------------------------------------------
// Blocks 0..3: convert wu_c into MFMA B-fragments (hi/lo bf16), lane-packed.
// B[k][n] = wu[n][k]; lane holds n=lane&15, k=kc*32+(lane>>4)*8+j.
// Blocks 4..16: LDS-privatized batch histogram (batch is sorted).
// -------------------------------------------------------------------------
#define HB_BAT 13

__global__ __launch_bounds__(256) void prep_small_kernel(
    const float* __restrict__ wu_e1, const float* __restrict__ wu_e2,
    const float* __restrict__ wu_i1, const float* __restrict__ wu_i2,
    const int* __restrict__ batch,
    unsigned short* __restrict__ WB, float* __restrict__ wcolp,
    int* __restrict__ cnt)
{
  const int b = blockIdx.x, t = threadIdx.x;
  if (b < 4) {
    const float* wu = (b == 0) ? wu_e1 : (b == 1) ? wu_e2 : (b == 2) ? wu_i1 : wu_i2;
    const int lane = t & 63, u = t >> 6;
    const int n = lane & 15, quad = lane >> 4;
    unsigned short* wb = WB + b * 32768;
    #pragma unroll
    for (int cc = 0; cc < 2; ++cc) {
      const int ct = u + 4 * cc;
      const int j = ct * 16 + n;
      #pragma unroll
      for (int kc = 0; kc < 4; ++kc) {
        const int k0 = kc * 32 + quad * 8;
        const float* src = wu + (size_t)j * 129 + k0;
        short8 hi, lo;
        #pragma unroll
        for (int e = 0; e < 8; ++e) {
          const float v = src[e];
          const unsigned short h = bf16h(v);
          hi[e] = (short)h;
          lo[e] = (short)bf16h(v - bf16tof(h));
        }
        const int fbase = ((ct * 4 + kc) * 2) * 512 + lane * 8;
        *(short8*)&wb[fbase]       = hi;
        *(short8*)&wb[fbase + 512] = lo;
      }
    }
    if (t < 128) wcolp[b * 128 + t] = wu[(size_t)t * 129 + 128];
  } else {
    __shared__ int h[64];
    if (t < 64) h[t] = 0;
    __syncthreads();
    const int base = (b - 4) * 4096 + t;
    for (int u = 0; u < 16; ++u) {
      const int i = base + u * 256;
      if (i < NN) atomicAdd(&h[batch[i]], 1);
    }
    __syncthreads();
    if (t < 64 && h[t]) atomicAdd(&cnt[t], h[t]);
  }
}

// -------------------------------------------------------------------------
// Fused conv chain via split-bf16 MFMA (hi*hi + hi*lo + lo*hi; lo*lo term
// dropped: ~4e-6 error vs 4.2e-5 threshold).  Grid (782, 2), 512 threads =
// 8 waves; wave w owns col-tile ct=w (16 cols), all 4 row-tiles.
// B fragments: 8 short8 = 32 VGPRs/wave.  A (X then y) in LDS fragment order.
// mfma_f32_16x16x32_bf16: A/B: m|n=lane&15, k=(lane>>4)*8+j ;
// D: col=lane&15, row=(lane>>4)*4+reg.
// LDS 34.8 KB -> 4 blocks/CU = 32 waves/CU.
// -------------------------------------------------------------------------
__global__ __launch_bounds__(512, 4) void conv_mfma_kernel(
    const float* __restrict__ x,
    const int* __restrict__ deg_ext, const int* __restrict__ deg_int,
    const int* __restrict__ batch,
    const unsigned short* __restrict__ WB, const float* __restrict__ wcolp,
    const float* __restrict__ bu_e1, const float* __restrict__ bu_e2,
    const float* __restrict__ bu_i1, const float* __restrict__ bu_i2,
    float* __restrict__ ez_sum, float* __restrict__ iz_sum)
{
  __shared__ unsigned short XT[2 * 8192];   // [part][rt*4+kc][qk*16+m][8]  32 KB
  __shared__ float red[64 * 8];             // per-row per-wave partials
  __shared__ float invb[64];
  __shared__ float degs[64];

  const int tid  = threadIdx.x;
  const int lane = tid & 63;
  const int w    = tid >> 6;        // wave 0..7 = col-tile
  const int n    = lane & 15;
  const int quad = lane >> 4;
  const int mbase = blockIdx.x * 64;
  const int chain = blockIdx.y;

  const int*  deg  = chain ? deg_int : deg_ext;
  float*      gsum = chain ? iz_sum  : ez_sum;
  const float* bu0 = chain ? bu_i1 : bu_e1;
  const float* bu1 = chain ? bu_i2 : bu_e2;

  // ---- stage X -> A fragments (hi/lo): thread = (node_local, 16-k group)
  {
    const int nl = tid >> 3;           // node_local 0..63
    const int ko = tid & 7;            // k-octet*2: k in [16ko, 16ko+16)
    const int node = mbase + nl;
    const int rt = nl >> 4, m = nl & 15;
    const float* xr = x + (size_t)node * FD + ko * 16;
    float4 v0 = make_float4(0,0,0,0), v1 = v0, v2 = v0, v3 = v0;
    if (node < NN) {
      v0 = *(const float4*)(xr + 0);
      v1 = *(const float4*)(xr + 4);
      v2 = *(const float4*)(xr + 8);
      v3 = *(const float4*)(xr + 12);
    }
    const float f[16] = {v0.x,v0.y,v0.z,v0.w, v1.x,v1.y,v1.z,v1.w,
                         v2.x,v2.y,v2.z,v2.w, v3.x,v3.y,v3.z,v3.w};
    #pragma unroll
    for (int g = 0; g < 2; ++g) {
      S8 hi, lo;
      #pragma unroll
      for (int p = 0; p < 4; ++p) {
        const float a = f[g * 8 + 2 * p], b = f[g * 8 + 2 * p + 1];
        const unsigned int uh = pk_bf16(a, b);
        const float la = a - __uint_as_float(uh << 16);
        const float lb = b - __uint_as_float(uh & 0xFFFF0000u);
        hi.u[p] = uh;
        lo.u[p] = pk_bf16(la, lb);
      }
      const int k0 = ko * 16 + g * 8;
      const int kc = k0 >> 5, qk = (k0 >> 3) & 3;
      const int idx = ((rt * 4 + kc) * 64 + qk * 16 + m) * 8;
      *(short8*)&XT[idx]        = hi.s;
      *(short8*)&XT[8192 + idx] = lo.s;
    }
    if (tid < 64) degs[tid] = (mbase + tid < NN) ? (float)deg[mbase + tid] : 0.f;
  }
  __syncthreads();

  f32x4 acc[4];

  for (int cv = 0; cv < 2; ++cv) {
    const int conv = chain * 2 + cv;
    const float* bu = cv ? bu1 : bu0;

    // ---- B fragments for col-tile ct=w (held in 32 VGPRs)
    short8 Bhi[4], Blo[4];
    {
      const unsigned short* wb = WB + conv * 32768 + w * 4096 + lane * 8;
      #pragma unroll
      for (int kc = 0; kc < 4; ++kc) {
        Bhi[kc] = *(const short8*)&wb[kc * 1024];
        Blo[kc] = *(const short8*)&wb[kc * 1024 + 512];
      }
    }

    #pragma unroll
    for (int rt = 0; rt < 4; ++rt) acc[rt] = (f32x4){0.f, 0.f, 0.f, 0.f};

    // ---- MFMA main loop (3-term split)
    #pragma unroll
    for (int rt = 0; rt < 4; ++rt) {
      const int abase = (rt * 4 * 64 + lane) * 8;
      short8 Ahi[4], Alo[4];
      #pragma unroll
      for (int kc = 0; kc < 4; ++kc) {
        Ahi[kc] = *(const short8*)&XT[abase + kc * 512];
        Alo[kc] = *(const short8*)&XT[8192 + abase + kc * 512];
      }
      f32x4 c = acc[rt];
      #pragma unroll
      for (int kc = 0; kc < 4; ++kc) {
        c = __builtin_amdgcn_mfma_f32_16x16x32_bf16(Ahi[kc], Bhi[kc], c, 0, 0, 0);
        c = __builtin_amdgcn_mfma_f32_16x16x32_bf16(Alo[kc], Bhi[kc], c, 0, 0, 0);
        c = __builtin_amdgcn_mfma_f32_16x16x32_bf16(Ahi[kc], Blo[kc], c, 0, 0, 0);
      }
      acc[rt] = c;
    }

    // ---- epilogue: + deg*wcol + bias, leaky_relu, exp (no max: |logit| small)
    const float bias = bu[16 * w + n];
    const float wc   = wcolp[conv * 128 + 16 * w + n];

    #pragma unroll
    for (int rt = 0; rt < 4; ++rt) {
      const float4 dg = *(const float4*)&degs[rt * 16 + quad * 4];
      const float dgv[4] = {dg.x, dg.y, dg.z, dg.w};
      #pragma unroll
      for (int r = 0; r < 4; ++r) {
        float v = acc[rt][r] + bias + dgv[r] * wc;
        v = (v > 0.f) ? v : 0.01f * v;
        const float e = __expf(v);
        acc[rt][r] = e;
        float s = e;
        s += __shfl_xor(s, 1);
        s += __shfl_xor(s, 2);
        s += __shfl_xor(s, 4);
        s += __shfl_xor(s, 8);
        if (n == 0) red[(rt * 16 + quad * 4 + r) * 8 + w] = s;
      }
    }
    __syncthreads();
    if (tid < 64) {
      const float4 p0 = *(const float4*)&red[tid * 8];
      const float4 p1 = *(const float4*)&red[tid * 8 + 4];
      invb[tid] = 1.f / (p0.x + p0.y + p0.z + p0.w + p1.x + p1.y + p1.z + p1.w);
    }
    __syncthreads();
    #pragma unroll
    for (int rt = 0; rt < 4; ++rt) {
      const float4 iv = *(const float4*)&invb[rt * 16 + quad * 4];
      const float ivv[4] = {iv.x, iv.y, iv.z, iv.w};
      #pragma unroll
      for (int r = 0; r < 4; ++r) acc[rt][r] *= ivv[r];
    }

    if (cv == 0) {
      // write y (hi/lo) into XT in A-fragment order for conv2:
      // col j = 16w+n -> kc'=w>>1, qk'=2(w&1)+(n>>3), e'=n&7 ; row m'=quad*4+r
      const int kcp = w >> 1;
      const int qkp = 2 * (w & 1) + (n >> 3);
      const int ep  = n & 7;
      #pragma unroll
      for (int rt = 0; rt < 4; ++rt) {
        const unsigned int uh01 = pk_bf16(acc[rt][0], acc[rt][1]);
        const unsigned int uh23 = pk_bf16(acc[rt][2], acc[rt][3]);
        const float l0 = acc[rt][0] - __uint_as_float(uh01 << 16);
        const float l1 = acc[rt][1] - __uint_as_float(uh01 & 0xFFFF0000u);
        const float l2 = acc[rt][2] - __uint_as_float(uh23 << 16);
        const float l3 = acc[rt][3] - __uint_as_float(uh23 & 0xFFFF0000u);
        const unsigned int ul01 = pk_bf16(l0, l1);
        const unsigned int ul23 = pk_bf16(l2, l3);
        const unsigned short h[4] = {(unsigned short)(uh01 & 0xFFFF), (unsigned short)(uh01 >> 16),
                                     (unsigned short)(uh23 & 0xFFFF), (unsigned short)(uh23 >> 16)};
        const unsigned short l[4] = {(unsigned short)(ul01 & 0xFFFF), (unsigned short)(ul01 >> 16),
                                     (unsigned short)(ul23 & 0xFFFF), (unsigned short)(ul23 >> 16)};
        #pragma unroll
        for (int r = 0; r < 4; ++r) {
          const int idx = ((rt * 4 + kcp) * 64 + qkp * 16 + quad * 4 + r) * 8 + ep;
          XT[idx]        = h[r];
          XT[8192 + idx] = l[r];
        }
      }
      __syncthreads();
    }
  }

  // ---- scatter into per-graph sums (batch sorted: one-graph fast path)
  {
    bool fast = false; int gall = 0;
    if (mbase + 63 < NN) { gall = batch[mbase]; fast = (batch[mbase + 63] == gall); }
    if (fast) {
      float s = 0.f;
      #pragma unroll
      for (int rt = 0; rt < 4; ++rt)
        #pragma unroll
        for (int r = 0; r < 4; ++r) s += acc[rt][r];
      s += __shfl_xor(s, 16);
      s += __shfl_xor(s, 32);
      if (quad == 0)
        atomicAdd(&gsum[gall * FD + 16 * w + n], s);
    } else {
      const int j = 16 * w + n;
      for (int rt = 0; rt < 4; ++rt) {
        for (int r = 0; r < 4; ++r) {
          const int node = mbase + rt * 16 + quad * 4 + r;
          if (node < NN) {
            const int g = batch[node];
            atomicAdd(&gsum[g * FD + j], acc[rt][r]);
          }
        }
      }
    }
  }
}

// -------------------------------------------------------------------------
// Final MLP: 8 blocks x 8 graphs.
// -------------------------------------------------------------------------
__global__ __launch_bounds__(256) void fc_kernel(
    const float* __restrict__ ez_sum, const float* __restrict__ iz_sum,
    const int* __restrict__ cnt,
    const float* __restrict__ fc1_w, const float* __restrict__ fc1_b,
    const float* __restrict__ fc2_w, const float* __restrict__ fc2_b,
    float* __restrict__ out)
{
  __shared__ float z8[8 * 256];
  __shared__ float h8[8 * 129];
  const int t = threadIdx.x;
  const int gbase = blockIdx.x * 8;

  for (int idx = t; idx < 8 * 256; idx += 256) {
    const int gl = idx >> 8, c = idx & 255;
    const int g = gbase + gl;
    const float denom = fmaxf((float)cnt[g], 1.0f);
    const float v = (c < 128 ? ez_sum[g * 128 + c] : iz_sum[g * 128 + (c - 128)]);
    z8[idx] = v / denom;
  }
  __syncthreads();

  {
    const int o = t & 127;
    const int gh = t >> 7;
    const float* w = fc1_w + (size_t)o * 256;
    float a0 = fc1_b[o], a1 = a0, a2 = a0, a3 = a0;
    const float* z0 = &z8[(gh * 4 + 0) * 256];
    const float* z1 = &z8[(gh * 4 + 1) * 256];
    const float* z2 = &z8[(gh * 4 + 2) * 256];
    const float* z3 = &z8[(gh * 4 + 3) * 256];
    for (int c = 0; c < 256; c += 4) {
      const float4 wv = *(const float4*)(w + c);
      const float4 v0 = *(const float4*)(z0 + c);
      const float4 v1 = *(const float4*)(z1 + c);
      const float4 v2 = *(const float4*)(z2 + c);
      const float4 v3 = *(const float4*)(z3 + c);
      a0 += wv.x * v0.x + wv.y * v0.y + wv.z * v0.z + wv.w * v0.w;
      a1 += wv.x * v1.x + wv.y * v1.y + wv.z * v1.z + wv.w * v1.w;
      a2 += wv.x * v2.x + wv.y * v2.y + wv.z * v2.z + wv.w * v2.w;
      a3 += wv.x * v3.x + wv.y * v3.y + wv.z * v3.z + wv.w * v3.w;
    }
    h8[(gh * 4 + 0) * 129 + o] = fmaxf(a0, 0.f);
    h8[(gh * 4 + 1) * 129 + o] = fmaxf(a1, 0.f);
    h8[(gh * 4 + 2) * 129 + o] = fmaxf(a2, 0.f);
    h8[(gh * 4 + 3) * 129 + o] = fmaxf(a3, 0.f);
  }
  __syncthreads();

  if (t < 8) {
    const float* hh = &h8[t * 129];
    float a = fc2_b[0];
    for (int o = 0; o < 128; ++o) a += hh[o] * fc2_w[o];
    out[gbase + t] = a;
  }
}

// -------------------------------------------------------------------------
extern "C" void kernel_launch(void* const* d_in, const int* in_sizes, int n_in,
                              void* d_out, int out_size, void* d_ws, size_t ws_size,
                              hipStream_t stream) {
  const float* x                   = (const float*)d_in[0];
  const int*   edge_index          = (const int*)  d_in[1];   // [2,E]: first E = sources
  const int*   internal_edge_index = (const int*)  d_in[3];
  const int*   batch               = (const int*)  d_in[5];
  const float* wu_e1 = (const float*)d_in[8];
  const float* bu_e1 = (const float*)d_in[9];
  const float* wu_e2 = (const float*)d_in[12];
  const float* bu_e2 = (const float*)d_in[13];
  const float* wu_i1 = (const float*)d_in[16];
  const float* bu_i1 = (const float*)d_in[17];
  const float* wu_i2 = (const float*)d_in[20];
  const float* bu_i2 = (const float*)d_in[21];
  const float* fc1_w = (const float*)d_in[22];
  const float* fc1_b = (const float*)d_in[23];
  const float* fc2_w = (const float*)d_in[24];
  const float* fc2_b = (const float*)d_in[25];

  char* ws = (char*)d_ws;
  int*   deg_ext = (int*)  (ws + DEG_EXT_OFF);
  int*   deg_int = (int*)  (ws + DEG_INT_OFF);
  float* ez      = (float*)(ws + EZ_OFF);
  float* iz      = (float*)(ws + IZ_OFF);
  int*   cnt     = (int*)  (ws + CNT_OFF);
  unsigned short* WB = (unsigned short*)(ws + WB_OFF);
  float* wcolp   = (float*)(ws + WCOL_OFF);

  hipMemsetAsync(d_ws, 0, ZERO_BYTES, stream);

  edge_hist_kernel<<<EB_EXT + EB_INT, 256, 0, stream>>>(
      (const int4*)edge_index, (const int4*)internal_edge_index,
      deg_ext, deg_int);

  prep_small_kernel<<<4 + HB_BAT, 256, 0, stream>>>(
      wu_e1, wu_e2, wu_i1, wu_i2, batch, WB, wcolp, cnt);

  conv_mfma_kernel<<<dim3((NN + 63) / 64, 2), 512, 0, stream>>>(
      x, deg_ext, deg_int, batch, WB, wcolp,
      bu_e1, bu_e2, bu_i1, bu_i2, ez, iz);

  fc_kernel<<<8, 256, 0, stream>>>(ez, iz, cnt, fc1_w, fc1_b, fc2_w, fc2_b,
                                   (float*)d_out);
}